// Round 12
// baseline (654.720 us; speedup 1.0000x reference)
//
#include <hip/hip_runtime.h>
#include <hip/hip_fp16.h>
#include <cmath>

#define NN 100000
#define EE 1600000
#define TOTE (EE + NN)
#define SHIFT 10
#define NBUK 98          // ceil(NN / 1024)
#define CAPB 18432       // per-bucket region capacity; mean 17408 +7 sigma
#define SLACK 5632       // per-bucket pad slack for x8 node padding
#define SPAN (TOTE + NBUK * SLACK)
#define PCAP 200         // per-wave LDS p capacity

typedef _Float16 half8_t __attribute__((ext_vector_type(8)));
typedef _Float16 half4_t __attribute__((ext_vector_type(4)));
typedef float float4_t __attribute__((ext_vector_type(4)));

__device__ __forceinline__ float lrelu(float v) { return v > 0.f ? v : 0.2f * v; }

// ---------------- CSR build: 2-phase bucket sort ----------------
__global__ __launch_bounds__(256) void binA(const int* __restrict__ src, const int* __restrict__ dst,
                                            int* __restrict__ gcur, int* __restrict__ region) {
    __shared__ int cnt[NBUK], gbase[NBUK], pos[NBUK];
    int t = threadIdx.x;
    if (t < NBUK) cnt[t] = 0;
    __syncthreads();
    const int CH = (TOTE + gridDim.x - 1) / gridDim.x;
    int lo = blockIdx.x * CH;
    int hi = lo + CH; if (hi > TOTE) hi = TOTE;
    for (int e = lo + t; e < hi; e += 256) {
        int d = (e < EE) ? dst[e] : (e - EE);
        atomicAdd(&cnt[d >> SHIFT], 1);
    }
    __syncthreads();
    if (t < NBUK) {
        gbase[t] = atomicAdd(&gcur[t], cnt[t]);
        pos[t] = 0;
    }
    __syncthreads();
    for (int e = lo + t; e < hi; e += 256) {
        int s, d;
        if (e < EE) { s = src[e]; d = dst[e]; }
        else        { s = e - EE; d = s; }
        int b = d >> SHIFT;
        int k = atomicAdd(&pos[b], 1);
        region[(size_t)b * CAPB + gbase[b] + k] = (s << SHIFT) | (d & 1023);
    }
}

// Phase B: per-node ranges padded to x8; pad slots get esrc=0 (p=0 later).
__global__ __launch_bounds__(1024) void binB(const int* __restrict__ region, const int* __restrict__ gcur,
                                             int2* __restrict__ rng, int* __restrict__ esrc) {
    __shared__ int ncur[1024];
    __shared__ int wsum[16];
    __shared__ int sg[NBUK];
    __shared__ int sBase;
    int b = blockIdx.x, t = threadIdx.x;
    int n0 = b << SHIFT;
    if (t < NBUK) sg[t] = gcur[t];
    ncur[t] = 0;
    __syncthreads();
    if (t == 0) {
        int run = 0;
        for (int bb = 0; bb < b; ++bb) run += sg[bb] + SLACK;
        sBase = run;
    }
    int cntE = gcur[b];
    const int* reg = region + (size_t)b * CAPB;
    __syncthreads();
    for (int i = t; i < cntE; i += 1024)
        atomicAdd(&ncur[reg[i] & 1023], 1);
    int base = sBase;
    __syncthreads();
    int v = ncur[t];
    int vp = (v + 7) & ~7;
    __syncthreads();
    int incl = vp;
    for (int off = 1; off < 64; off <<= 1) {
        int u = __shfl_up(incl, off);
        if ((t & 63) >= off) incl += u;
    }
    if ((t & 63) == 63) wsum[t >> 6] = incl;
    __syncthreads();
    if (t < 16) {
        int w = wsum[t];
        int winc = w;
        for (int off = 1; off < 16; off <<= 1) {
            int u = __shfl_up(winc, off);
            if (t >= off) winc += u;
        }
        wsum[t] = winc - w;
    }
    __syncthreads();
    int excl = incl - vp + wsum[t >> 6];
    int start = base + excl;
    int n = n0 + t;
    if (n < NN) rng[n] = make_int2(start, v);
    ncur[t] = start;
    __syncthreads();
    for (int i = t; i < cntE; i += 1024) {
        int p = reg[i];
        int local = p & 1023;
        int k = atomicAdd(&ncur[local], 1);
        esrc[k] = p >> SHIFT;
    }
    __syncthreads();
    if (n < NN) {
        for (int k = start + v; k < start + vp; ++k) esrc[k] = 0;
    }
}

// ---------------- MFMA GEMM + fused attention coefficients ----------------
template <int K, bool F32IN>
__global__ __launch_bounds__(256) void gemm_attn(const void* __restrict__ Xv, const float* __restrict__ W,
                                                 const float* __restrict__ a_src, const float* __restrict__ a_dst,
                                                 _Float16* __restrict__ H, float* __restrict__ asrc,
                                                 float* __restrict__ adst) {
    __shared__ _Float16 wt[64][K + 8];
    int t = threadIdx.x;
    for (int it = 0; it < K / 16; ++it) {
        int idx4 = it * 256 + t;
        int k = idx4 >> 4;
        int n4 = (idx4 * 4) & 63;
        float4 v = *(const float4*)(W + (size_t)idx4 * 4);
        wt[n4 + 0][k] = (_Float16)v.x;
        wt[n4 + 1][k] = (_Float16)v.y;
        wt[n4 + 2][k] = (_Float16)v.z;
        wt[n4 + 3][k] = (_Float16)v.w;
    }
    __syncthreads();

    int row0 = blockIdx.x * 64;
    int wr = (t >> 6) * 16;
    int lane = t & 63;
    int m = lane & 15;
    int q = lane >> 4;

    int rowA = row0 + wr + m;
    if (rowA >= NN) rowA = NN - 1;

    float4_t acc[4] = { {0,0,0,0}, {0,0,0,0}, {0,0,0,0}, {0,0,0,0} };
#pragma unroll
    for (int kc = 0; kc < K / 32; ++kc) {
        half8_t av;
        if (F32IN) {
            const float* xrow = (const float*)Xv + (size_t)rowA * K + q * 8;
            float4 u0 = *(const float4*)(xrow + kc * 32);
            float4 u1 = *(const float4*)(xrow + kc * 32 + 4);
            av[0] = (_Float16)u0.x; av[1] = (_Float16)u0.y;
            av[2] = (_Float16)u0.z; av[3] = (_Float16)u0.w;
            av[4] = (_Float16)u1.x; av[5] = (_Float16)u1.y;
            av[6] = (_Float16)u1.z; av[7] = (_Float16)u1.w;
        } else {
            const _Float16* xrow = (const _Float16*)Xv + (size_t)rowA * K + q * 8;
            av = *(const half8_t*)(xrow + kc * 32);
        }
#pragma unroll
        for (int c = 0; c < 4; ++c) {
            half8_t bv = *(const half8_t*)&wt[c * 16 + m][kc * 32 + q * 8];
            acc[c] = __builtin_amdgcn_mfma_f32_16x16x32_f16(av, bv, acc[c], 0, 0, 0);
        }
    }

#pragma unroll
    for (int r = 0; r < 4; ++r) {
        int row = row0 + wr + q * 4 + r;
        if (row < NN) {
#pragma unroll
            for (int c = 0; c < 4; ++c)
                H[(size_t)row * 64 + c * 16 + m] = (_Float16)acc[c][r];
        }
    }

    float as0 = a_src[m], as1 = a_src[16 + m], as2 = a_src[32 + m], as3 = a_src[48 + m];
    float ad0 = a_dst[m], ad1 = a_dst[16 + m], ad2 = a_dst[32 + m], ad3 = a_dst[48 + m];
#pragma unroll
    for (int r = 0; r < 4; ++r) {
        float s0 = acc[0][r] * as0 + acc[1][r] * as1;
        float s1 = acc[2][r] * as2 + acc[3][r] * as3;
        float d0 = acc[0][r] * ad0 + acc[1][r] * ad1;
        float d1 = acc[2][r] * ad2 + acc[3][r] * ad3;
#pragma unroll
        for (int mk = 1; mk < 16; mk <<= 1) {
            s0 += __shfl_xor(s0, mk);
            s1 += __shfl_xor(s1, mk);
            d0 += __shfl_xor(d0, mk);
            d1 += __shfl_xor(d1, mk);
        }
        int row = row0 + wr + q * 4 + r;
        if (m == 0 && row < NN) {
            asrc[2 * row + 0] = s0;
            asrc[2 * row + 1] = s1;
            adst[2 * row + 0] = d0;
            adst[2 * row + 1] = d1;
        }
    }
}

// ---------------- edge aggregation (wave per node, packed p+s in LDS) ---------
// Phase 1: lane-per-edge computes (p0,p1) once and packs (p0,p1,src) into one
// float4 LDS slot. Phase 2: lane = eo(8 slots) x c8(8 channels); per edge-slot
// one ds_read_b128 (p+s) and one 16B half8 h load. 8 edges in flight/iter.
// MODE 0: write ixbuf, xout=elu(t); MODE 1: t+=ixbuf; MODE 2: t+=ixbuf then
// out-projection h_o = x.Wo.
template <int MODE>
__global__ __launch_bounds__(256) void edge_agg(const int2* __restrict__ rng, const int* __restrict__ esrc,
                                                const _Float16* __restrict__ h, const float* __restrict__ asrc,
                                                const float* __restrict__ adst, const float* __restrict__ bias,
                                                _Float16* __restrict__ ixbuf, _Float16* __restrict__ xout,
                                                const float* __restrict__ Wo, const float* __restrict__ a_s,
                                                const float* __restrict__ a_d, float* __restrict__ h_o,
                                                float* __restrict__ asrc_o, float* __restrict__ adst_o) {
    __shared__ float4 pLDS[4][PCAP];
    int n = (blockIdx.x * 256 + threadIdx.x) >> 6;
    if (n >= NN) return;
    int wq = threadIdx.x >> 6;
    int lane = threadIdx.x & 63;
    int2 r = rng[n];
    int start = r.x, deg = r.y;
    int vp = (deg + 7) & ~7;
    if (vp > PCAP) vp = PCAP;
    float2 ad = *(const float2*)(adst + 2 * (size_t)n);
    // phase 1: (p0, p1, src) per edge, one lane per edge
    for (int j = lane; j < vp; j += 64) {
        float p0 = 0.f, p1 = 0.f;
        int s = 0;
        if (j < deg) {
            s = esrc[start + j];
            float2 as = *(const float2*)(asrc + 2 * (size_t)s);
            p0 = __expf(fminf(lrelu(as.x + ad.x), 60.f));
            p1 = __expf(fminf(lrelu(as.y + ad.y), 60.f));
        }
        pLDS[wq][j] = make_float4(p0, p1, __int_as_float(s), 0.f);
    }
    // phase 2: p-weighted gather, 8 edge slots x 8 channels
    int eo = lane >> 3;
    int c8 = lane & 7;
    int head = c8 >> 2;
    const _Float16* hrow = h + 8 * c8;
    float acc[8] = {0.f, 0.f, 0.f, 0.f, 0.f, 0.f, 0.f, 0.f};
    float lsum = 0.f;
    for (int j = 0; j < vp; j += 8) {
        float4 pj = pLDS[wq][j + eo];
        int s = __float_as_int(pj.z);
        float w = head ? pj.y : pj.x;
        half8_t hv = *(const half8_t*)(hrow + (size_t)s * 64);
        lsum += w;
#pragma unroll
        for (int k = 0; k < 8; ++k) acc[k] += w * (float)hv[k];
    }
    // merge the 8 edge slots (lane bits 3..5)
#pragma unroll
    for (int mm = 8; mm <= 32; mm <<= 1) {
        lsum += __shfl_xor(lsum, mm);
#pragma unroll
        for (int k = 0; k < 8; ++k) acc[k] += __shfl_xor(acc[k], mm);
    }
    if (eo == 0) {
        float inv = 1.f / lsum;
        float4 b0 = *(const float4*)(bias + 8 * c8);
        float4 b1 = *(const float4*)(bias + 8 * c8 + 4);
        float tv[8];
        tv[0] = acc[0] * inv + b0.x; tv[1] = acc[1] * inv + b0.y;
        tv[2] = acc[2] * inv + b0.z; tv[3] = acc[3] * inv + b0.w;
        tv[4] = acc[4] * inv + b1.x; tv[5] = acc[5] * inv + b1.y;
        tv[6] = acc[6] * inv + b1.z; tv[7] = acc[7] * inv + b1.w;
        if (MODE == 0) {
            half8_t iw;
#pragma unroll
            for (int k = 0; k < 8; ++k) iw[k] = (_Float16)tv[k];
            *(half8_t*)(ixbuf + (size_t)n * 64 + 8 * c8) = iw;
        } else {
            half8_t iv = *(const half8_t*)(ixbuf + (size_t)n * 64 + 8 * c8);
#pragma unroll
            for (int k = 0; k < 8; ++k) tv[k] += (float)iv[k];
        }
#pragma unroll
        for (int k = 0; k < 8; ++k) tv[k] = tv[k] > 0.f ? tv[k] : __expf(tv[k]) - 1.f;
        if (MODE != 2) {
            half8_t o;
#pragma unroll
            for (int k = 0; k < 8; ++k) o[k] = (_Float16)tv[k];
            *(half8_t*)(xout + (size_t)n * 64 + 8 * c8) = o;
        } else {
            float4 w0 = *(const float4*)(Wo + 8 * c8);
            float4 w1 = *(const float4*)(Wo + 8 * c8 + 4);
            float v = tv[0] * w0.x + tv[1] * w0.y + tv[2] * w0.z + tv[3] * w0.w
                    + tv[4] * w1.x + tv[5] * w1.y + tv[6] * w1.z + tv[7] * w1.w;
            v += __shfl_xor(v, 1);
            v += __shfl_xor(v, 2);
            v += __shfl_xor(v, 4);
            if (c8 == 0) {
                h_o[n] = v;
                asrc_o[n] = v * a_s[0];
                adst_o[n] = v * a_d[0];
            }
        }
    }
}

// ---------------- output-layer edge aggregation ----------------
__global__ __launch_bounds__(256) void edge_agg_out(const int2* __restrict__ rng, const int* __restrict__ esrc,
                                                    const float* __restrict__ h_o, const float* __restrict__ asrc_o,
                                                    const float* __restrict__ adst_o, const float* __restrict__ b_out,
                                                    float* __restrict__ out) {
    int n = (blockIdx.x * 256 + threadIdx.x) >> 6;
    if (n >= NN) return;
    int lane = threadIdx.x & 63;
    int2 r = rng[n];
    int rs = r.x, re = r.x + r.y;
    float adv = adst_o[n];
    float l = 0.f, acc = 0.f;
    for (int i = rs + lane; i < re; i += 64) {
        int s = esrc[i];
        float e = fminf(lrelu(asrc_o[s] + adv), 60.f);
        float p = __expf(e);
        l += p;
        acc = fmaf(p, h_o[s], acc);
    }
    for (int mm = 32; mm >= 1; mm >>= 1) {
        l += __shfl_xor(l, mm);
        acc += __shfl_xor(acc, mm);
    }
    if (lane == 0) out[n] = 1.f / (1.f + __expf(-(acc / l + b_out[0])));
}

// ---------------- launch ----------------
extern "C" void kernel_launch(void* const* d_in, const int* in_sizes, int n_in,
                              void* d_out, int out_size, void* d_ws, size_t ws_size,
                              hipStream_t stream) {
    const float* node_attrs = (const float*)d_in[0];
    const int*   edge_index = (const int*)d_in[1];
    const float* W_in      = (const float*)d_in[2];
    const float* a_src_in  = (const float*)d_in[3];
    const float* a_dst_in  = (const float*)d_in[4];
    const float* b_in      = (const float*)d_in[5];
    const float* W_mid     = (const float*)d_in[6];
    const float* a_src_mid = (const float*)d_in[7];
    const float* a_dst_mid = (const float*)d_in[8];
    const float* b_mid     = (const float*)d_in[9];
    const float* W_out     = (const float*)d_in[10];
    const float* a_src_out = (const float*)d_in[11];
    const float* a_dst_out = (const float*)d_in[12];
    const float* b_out     = (const float*)d_in[13];
    float* out = (float*)d_out;

    const int* srcArr = edge_index;
    const int* dstArr = edge_index + EE;

    char* w = (char*)d_ws;
    auto alloc = [&](size_t bytes) { void* p = (void*)w; w += (bytes + 255) & ~(size_t)255; return p; };
    int2*  rng        = (int2*)alloc((size_t)NN * 8);
    int*   gcur       = (int*)alloc((size_t)NBUK * 4);
    int*   region     = (int*)alloc((size_t)NBUK * CAPB * 4);
    int*   esrc       = (int*)alloc((size_t)SPAN * 4);
    _Float16* h       = (_Float16*)alloc((size_t)NN * 64 * 2);
    _Float16* x16     = (_Float16*)alloc((size_t)NN * 64 * 2);
    _Float16* ixbuf   = (_Float16*)alloc((size_t)NN * 64 * 2);
    float* asrc       = (float*)alloc((size_t)NN * 2 * 4);
    float* adst       = (float*)alloc((size_t)NN * 2 * 4);
    float* h_o        = (float*)alloc((size_t)NN * 4);
    float* asrc_o     = (float*)alloc((size_t)NN * 4);
    float* adst_o     = (float*)alloc((size_t)NN * 4);

    // CSR build (padded)
    hipMemsetAsync(gcur, 0, NBUK * 4, stream);
    binA<<<256, 256, 0, stream>>>(srcArr, dstArr, gcur, region);
    binB<<<NBUK, 1024, 0, stream>>>(region, gcur, rng, esrc);

    int gemmBlocks = (NN + 63) / 64;
    int nodeBlocks = (NN + 3) / 4;

    // input layer (reads f32 node_attrs directly)
    gemm_attn<128, true><<<gemmBlocks, 256, 0, stream>>>(node_attrs, W_in, a_src_in, a_dst_in, h, asrc, adst);
    edge_agg<0><<<nodeBlocks, 256, 0, stream>>>(rng, esrc, h, asrc, adst, b_in, ixbuf, x16,
                                                nullptr, nullptr, nullptr, nullptr, nullptr, nullptr);

    // 5 mid layers (shared weights), then the 6th mid agg fused with out-projection
    for (int l = 0; l < 5; ++l) {
        gemm_attn<64, false><<<gemmBlocks, 256, 0, stream>>>(x16, W_mid, a_src_mid, a_dst_mid, h, asrc, adst);
        edge_agg<1><<<nodeBlocks, 256, 0, stream>>>(rng, esrc, h, asrc, adst, b_mid, ixbuf, x16,
                                                    nullptr, nullptr, nullptr, nullptr, nullptr, nullptr);
    }
    gemm_attn<64, false><<<gemmBlocks, 256, 0, stream>>>(x16, W_mid, a_src_mid, a_dst_mid, h, asrc, adst);
    edge_agg<2><<<nodeBlocks, 256, 0, stream>>>(rng, esrc, h, asrc, adst, b_mid, ixbuf, nullptr,
                                                W_out, a_src_out, a_dst_out, h_o, asrc_o, adst_o);

    // final softmax-aggregation + sigmoid
    edge_agg_out<<<nodeBlocks, 256, 0, stream>>>(rng, esrc, h_o, asrc_o, adst_o, b_out, out);
}

// Round 13
// 634.569 us; speedup vs baseline: 1.0318x; 1.0318x over previous
//
#include <hip/hip_runtime.h>
#include <hip/hip_fp16.h>
#include <cmath>

#define NN 100000
#define EE 1600000
#define TOTE (EE + NN)
#define SHIFT 10
#define NBUK 98          // ceil(NN / 1024)
#define CAPB 18432       // per-bucket region capacity; mean 17408 +7 sigma
#define SLACK 5632       // per-bucket pad slack for x8 node padding
#define SPAN (TOTE + NBUK * SLACK)
#define PCAP 200         // per-wave LDS p capacity

// Channel layout: logical ch = c*16 + m  <->  physical p = m*4 + c.
// h / x16 / ixbuf are stored PHYSICAL; W-staging permutes K to match;
// epilogues index bias/Wo at logical (k*16 + c4).

typedef _Float16 half8_t __attribute__((ext_vector_type(8)));
typedef _Float16 half4_t __attribute__((ext_vector_type(4)));
typedef float float4_t __attribute__((ext_vector_type(4)));

__device__ __forceinline__ float lrelu(float v) { return v > 0.f ? v : 0.2f * v; }

// ---------------- CSR build: 2-phase bucket sort ----------------
__global__ __launch_bounds__(256) void binA(const int* __restrict__ src, const int* __restrict__ dst,
                                            int* __restrict__ gcur, int* __restrict__ region) {
    __shared__ int cnt[NBUK], gbase[NBUK], pos[NBUK];
    int t = threadIdx.x;
    if (t < NBUK) cnt[t] = 0;
    __syncthreads();
    const int CH = (TOTE + gridDim.x - 1) / gridDim.x;
    int lo = blockIdx.x * CH;
    int hi = lo + CH; if (hi > TOTE) hi = TOTE;
    for (int e = lo + t; e < hi; e += 256) {
        int d = (e < EE) ? dst[e] : (e - EE);
        atomicAdd(&cnt[d >> SHIFT], 1);
    }
    __syncthreads();
    if (t < NBUK) {
        gbase[t] = atomicAdd(&gcur[t], cnt[t]);
        pos[t] = 0;
    }
    __syncthreads();
    for (int e = lo + t; e < hi; e += 256) {
        int s, d;
        if (e < EE) { s = src[e]; d = dst[e]; }
        else        { s = e - EE; d = s; }
        int b = d >> SHIFT;
        int k = atomicAdd(&pos[b], 1);
        region[(size_t)b * CAPB + gbase[b] + k] = (s << SHIFT) | (d & 1023);
    }
}

// Phase B: per-node ranges padded to x8; pad slots get esrc=0 (p=0 later).
__global__ __launch_bounds__(1024) void binB(const int* __restrict__ region, const int* __restrict__ gcur,
                                             int2* __restrict__ rng, int* __restrict__ esrc) {
    __shared__ int ncur[1024];
    __shared__ int wsum[16];
    __shared__ int sg[NBUK];
    __shared__ int sBase;
    int b = blockIdx.x, t = threadIdx.x;
    int n0 = b << SHIFT;
    if (t < NBUK) sg[t] = gcur[t];
    ncur[t] = 0;
    __syncthreads();
    if (t == 0) {
        int run = 0;
        for (int bb = 0; bb < b; ++bb) run += sg[bb] + SLACK;
        sBase = run;
    }
    int cntE = gcur[b];
    const int* reg = region + (size_t)b * CAPB;
    __syncthreads();
    for (int i = t; i < cntE; i += 1024)
        atomicAdd(&ncur[reg[i] & 1023], 1);
    int base = sBase;
    __syncthreads();
    int v = ncur[t];
    int vp = (v + 7) & ~7;
    __syncthreads();
    int incl = vp;
    for (int off = 1; off < 64; off <<= 1) {
        int u = __shfl_up(incl, off);
        if ((t & 63) >= off) incl += u;
    }
    if ((t & 63) == 63) wsum[t >> 6] = incl;
    __syncthreads();
    if (t < 16) {
        int w = wsum[t];
        int winc = w;
        for (int off = 1; off < 16; off <<= 1) {
            int u = __shfl_up(winc, off);
            if (t >= off) winc += u;
        }
        wsum[t] = winc - w;
    }
    __syncthreads();
    int excl = incl - vp + wsum[t >> 6];
    int start = base + excl;
    int n = n0 + t;
    if (n < NN) rng[n] = make_int2(start, v);
    ncur[t] = start;
    __syncthreads();
    for (int i = t; i < cntE; i += 1024) {
        int p = reg[i];
        int local = p & 1023;
        int k = atomicAdd(&ncur[local], 1);
        esrc[k] = p >> SHIFT;
    }
    __syncthreads();
    if (n < NN) {
        for (int k = start + v; k < start + vp; ++k) esrc[k] = 0;
    }
}

// ---------------- MFMA GEMM + fused attention coefficients ----------------
// H stored PHYSICAL (half4 per row per lane). Mid layers (F32IN=false) read
// physical x16, so wt K-rows are permuted at staging to match.
template <int K, bool F32IN>
__global__ __launch_bounds__(256) void gemm_attn(const void* __restrict__ Xv, const float* __restrict__ W,
                                                 const float* __restrict__ a_src, const float* __restrict__ a_dst,
                                                 _Float16* __restrict__ H, float* __restrict__ asrc,
                                                 float* __restrict__ adst) {
    __shared__ _Float16 wt[64][K + 8];
    int t = threadIdx.x;
    for (int it = 0; it < K / 16; ++it) {
        int idx4 = it * 256 + t;
        int k = idx4 >> 4;                   // logical input channel (row of W)
        int n4 = (idx4 * 4) & 63;
        int ks = F32IN ? k : ((k & 15) * 4 + (k >> 4));   // permute K for physical X
        float4 v = *(const float4*)(W + (size_t)idx4 * 4);
        wt[n4 + 0][ks] = (_Float16)v.x;
        wt[n4 + 1][ks] = (_Float16)v.y;
        wt[n4 + 2][ks] = (_Float16)v.z;
        wt[n4 + 3][ks] = (_Float16)v.w;
    }
    __syncthreads();

    int row0 = blockIdx.x * 64;
    int wr = (t >> 6) * 16;
    int lane = t & 63;
    int m = lane & 15;
    int q = lane >> 4;

    int rowA = row0 + wr + m;
    if (rowA >= NN) rowA = NN - 1;

    float4_t acc[4] = { {0,0,0,0}, {0,0,0,0}, {0,0,0,0}, {0,0,0,0} };
#pragma unroll
    for (int kc = 0; kc < K / 32; ++kc) {
        half8_t av;
        if (F32IN) {
            const float* xrow = (const float*)Xv + (size_t)rowA * K + q * 8;
            float4 u0 = *(const float4*)(xrow + kc * 32);
            float4 u1 = *(const float4*)(xrow + kc * 32 + 4);
            av[0] = (_Float16)u0.x; av[1] = (_Float16)u0.y;
            av[2] = (_Float16)u0.z; av[3] = (_Float16)u0.w;
            av[4] = (_Float16)u1.x; av[5] = (_Float16)u1.y;
            av[6] = (_Float16)u1.z; av[7] = (_Float16)u1.w;
        } else {
            const _Float16* xrow = (const _Float16*)Xv + (size_t)rowA * K + q * 8;
            av = *(const half8_t*)(xrow + kc * 32);
        }
#pragma unroll
        for (int c = 0; c < 4; ++c) {
            half8_t bv = *(const half8_t*)&wt[c * 16 + m][kc * 32 + q * 8];
            acc[c] = __builtin_amdgcn_mfma_f32_16x16x32_f16(av, bv, acc[c], 0, 0, 0);
        }
    }

    // store H physical: lane (m,q) row r -> one half4 at offset m*4
#pragma unroll
    for (int r = 0; r < 4; ++r) {
        int row = row0 + wr + q * 4 + r;
        if (row < NN) {
            half4_t hv = { (_Float16)acc[0][r], (_Float16)acc[1][r],
                           (_Float16)acc[2][r], (_Float16)acc[3][r] };
            *(half4_t*)(H + (size_t)row * 64 + m * 4) = hv;
        }
    }

    float as0 = a_src[m], as1 = a_src[16 + m], as2 = a_src[32 + m], as3 = a_src[48 + m];
    float ad0 = a_dst[m], ad1 = a_dst[16 + m], ad2 = a_dst[32 + m], ad3 = a_dst[48 + m];
#pragma unroll
    for (int r = 0; r < 4; ++r) {
        float s0 = acc[0][r] * as0 + acc[1][r] * as1;
        float s1 = acc[2][r] * as2 + acc[3][r] * as3;
        float d0 = acc[0][r] * ad0 + acc[1][r] * ad1;
        float d1 = acc[2][r] * ad2 + acc[3][r] * ad3;
#pragma unroll
        for (int mk = 1; mk < 16; mk <<= 1) {
            s0 += __shfl_xor(s0, mk);
            s1 += __shfl_xor(s1, mk);
            d0 += __shfl_xor(d0, mk);
            d1 += __shfl_xor(d1, mk);
        }
        int row = row0 + wr + q * 4 + r;
        if (m == 0 && row < NN) {
            asrc[2 * row + 0] = s0;
            asrc[2 * row + 1] = s1;
            adst[2 * row + 0] = d0;
            adst[2 * row + 1] = d1;
        }
    }
}

// ---------------- edge aggregation (wave per node, packed p+s in LDS) ---------
// Phase 1: lane-per-edge packs (p0,p1,src) into one float4 LDS slot.
// Phase 2: 16 lanes (c4 = physical quad) x 4 edge slots (eo); 2 edges per lane
// per iter -> 2 independent h loads in flight. Physical quad 4c4..4c4+3 maps to
// logical channels {c4, 16+c4, 32+c4, 48+c4} = heads {0,0,1,1}.
template <int MODE>
__global__ __launch_bounds__(256) void edge_agg(const int2* __restrict__ rng, const int* __restrict__ esrc,
                                                const _Float16* __restrict__ h, const float* __restrict__ asrc,
                                                const float* __restrict__ adst, const float* __restrict__ bias,
                                                _Float16* __restrict__ ixbuf, _Float16* __restrict__ xout,
                                                const float* __restrict__ Wo, const float* __restrict__ a_s,
                                                const float* __restrict__ a_d, float* __restrict__ h_o,
                                                float* __restrict__ asrc_o, float* __restrict__ adst_o) {
    __shared__ float4 pLDS[4][PCAP];
    int n = (blockIdx.x * 256 + threadIdx.x) >> 6;
    if (n >= NN) return;
    int wq = threadIdx.x >> 6;
    int lane = threadIdx.x & 63;
    int2 r = rng[n];
    int start = r.x, deg = r.y;
    int vp = (deg + 7) & ~7;
    if (vp > PCAP) vp = PCAP;
    float2 ad = *(const float2*)(adst + 2 * (size_t)n);
    // phase 1: (p0, p1, src) per edge, one lane per edge
    for (int j = lane; j < vp; j += 64) {
        float p0 = 0.f, p1 = 0.f;
        int s = 0;
        if (j < deg) {
            s = esrc[start + j];
            float2 as = *(const float2*)(asrc + 2 * (size_t)s);
            p0 = __expf(fminf(lrelu(as.x + ad.x), 60.f));
            p1 = __expf(fminf(lrelu(as.y + ad.y), 60.f));
        }
        pLDS[wq][j] = make_float4(p0, p1, __int_as_float(s), 0.f);
    }
    // phase 2
    int eo = lane >> 4;
    int c4 = lane & 15;
    const _Float16* hb = h + 4 * c4;
    float a0 = 0.f, a1 = 0.f, a2 = 0.f, a3 = 0.f, l0 = 0.f, l1 = 0.f;
    for (int j = 0; j < vp; j += 8) {
        float4 pA = pLDS[wq][j + eo];
        float4 pB = pLDS[wq][j + eo + 4];
        int sA = __float_as_int(pA.z);
        int sB = __float_as_int(pB.z);
        half4_t hA = *(const half4_t*)(hb + (size_t)sA * 64);
        half4_t hB = *(const half4_t*)(hb + (size_t)sB * 64);
        l0 += pA.x + pB.x;
        l1 += pA.y + pB.y;
        a0 += pA.x * (float)hA[0] + pB.x * (float)hB[0];
        a1 += pA.x * (float)hA[1] + pB.x * (float)hB[1];
        a2 += pA.y * (float)hA[2] + pB.y * (float)hB[2];
        a3 += pA.y * (float)hA[3] + pB.y * (float)hB[3];
    }
    // merge the 4 edge slots
#pragma unroll
    for (int mm = 16; mm <= 32; mm <<= 1) {
        a0 += __shfl_xor(a0, mm); a1 += __shfl_xor(a1, mm);
        a2 += __shfl_xor(a2, mm); a3 += __shfl_xor(a3, mm);
        l0 += __shfl_xor(l0, mm); l1 += __shfl_xor(l1, mm);
    }
    if (eo == 0) {
        float inv0 = 1.f / l0, inv1 = 1.f / l1;
        // logical indices for physical quad: k*16 + c4
        float t0 = a0 * inv0 + bias[c4];
        float t1 = a1 * inv0 + bias[16 + c4];
        float t2 = a2 * inv1 + bias[32 + c4];
        float t3 = a3 * inv1 + bias[48 + c4];
        if (MODE == 0) {
            half4_t iw = { (_Float16)t0, (_Float16)t1, (_Float16)t2, (_Float16)t3 };
            *(half4_t*)(ixbuf + (size_t)n * 64 + 4 * c4) = iw;
        } else {
            half4_t iv = *(const half4_t*)(ixbuf + (size_t)n * 64 + 4 * c4);
            t0 += (float)iv[0]; t1 += (float)iv[1]; t2 += (float)iv[2]; t3 += (float)iv[3];
        }
        t0 = t0 > 0.f ? t0 : __expf(t0) - 1.f;
        t1 = t1 > 0.f ? t1 : __expf(t1) - 1.f;
        t2 = t2 > 0.f ? t2 : __expf(t2) - 1.f;
        t3 = t3 > 0.f ? t3 : __expf(t3) - 1.f;
        if (MODE != 2) {
            half4_t o = { (_Float16)t0, (_Float16)t1, (_Float16)t2, (_Float16)t3 };
            *(half4_t*)(xout + (size_t)n * 64 + 4 * c4) = o;
        } else {
            float v = t0 * Wo[c4] + t1 * Wo[16 + c4] + t2 * Wo[32 + c4] + t3 * Wo[48 + c4];
            v += __shfl_xor(v, 1);
            v += __shfl_xor(v, 2);
            v += __shfl_xor(v, 4);
            v += __shfl_xor(v, 8);
            if (c4 == 0) {
                h_o[n] = v;
                asrc_o[n] = v * a_s[0];
                adst_o[n] = v * a_d[0];
            }
        }
    }
}

// ---------------- output-layer edge aggregation ----------------
__global__ __launch_bounds__(256) void edge_agg_out(const int2* __restrict__ rng, const int* __restrict__ esrc,
                                                    const float* __restrict__ h_o, const float* __restrict__ asrc_o,
                                                    const float* __restrict__ adst_o, const float* __restrict__ b_out,
                                                    float* __restrict__ out) {
    int n = (blockIdx.x * 256 + threadIdx.x) >> 6;
    if (n >= NN) return;
    int lane = threadIdx.x & 63;
    int2 r = rng[n];
    int rs = r.x, re = r.x + r.y;
    float adv = adst_o[n];
    float l = 0.f, acc = 0.f;
    for (int i = rs + lane; i < re; i += 64) {
        int s = esrc[i];
        float e = fminf(lrelu(asrc_o[s] + adv), 60.f);
        float p = __expf(e);
        l += p;
        acc = fmaf(p, h_o[s], acc);
    }
    for (int mm = 32; mm >= 1; mm >>= 1) {
        l += __shfl_xor(l, mm);
        acc += __shfl_xor(acc, mm);
    }
    if (lane == 0) out[n] = 1.f / (1.f + __expf(-(acc / l + b_out[0])));
}

// ---------------- launch ----------------
extern "C" void kernel_launch(void* const* d_in, const int* in_sizes, int n_in,
                              void* d_out, int out_size, void* d_ws, size_t ws_size,
                              hipStream_t stream) {
    const float* node_attrs = (const float*)d_in[0];
    const int*   edge_index = (const int*)d_in[1];
    const float* W_in      = (const float*)d_in[2];
    const float* a_src_in  = (const float*)d_in[3];
    const float* a_dst_in  = (const float*)d_in[4];
    const float* b_in      = (const float*)d_in[5];
    const float* W_mid     = (const float*)d_in[6];
    const float* a_src_mid = (const float*)d_in[7];
    const float* a_dst_mid = (const float*)d_in[8];
    const float* b_mid     = (const float*)d_in[9];
    const float* W_out     = (const float*)d_in[10];
    const float* a_src_out = (const float*)d_in[11];
    const float* a_dst_out = (const float*)d_in[12];
    const float* b_out     = (const float*)d_in[13];
    float* out = (float*)d_out;

    const int* srcArr = edge_index;
    const int* dstArr = edge_index + EE;

    char* w = (char*)d_ws;
    auto alloc = [&](size_t bytes) { void* p = (void*)w; w += (bytes + 255) & ~(size_t)255; return p; };
    int2*  rng        = (int2*)alloc((size_t)NN * 8);
    int*   gcur       = (int*)alloc((size_t)NBUK * 4);
    int*   region     = (int*)alloc((size_t)NBUK * CAPB * 4);
    int*   esrc       = (int*)alloc((size_t)SPAN * 4);
    _Float16* h       = (_Float16*)alloc((size_t)NN * 64 * 2);
    _Float16* x16     = (_Float16*)alloc((size_t)NN * 64 * 2);
    _Float16* ixbuf   = (_Float16*)alloc((size_t)NN * 64 * 2);
    float* asrc       = (float*)alloc((size_t)NN * 2 * 4);
    float* adst       = (float*)alloc((size_t)NN * 2 * 4);
    float* h_o        = (float*)alloc((size_t)NN * 4);
    float* asrc_o     = (float*)alloc((size_t)NN * 4);
    float* adst_o     = (float*)alloc((size_t)NN * 4);

    // CSR build (padded)
    hipMemsetAsync(gcur, 0, NBUK * 4, stream);
    binA<<<256, 256, 0, stream>>>(srcArr, dstArr, gcur, region);
    binB<<<NBUK, 1024, 0, stream>>>(region, gcur, rng, esrc);

    int gemmBlocks = (NN + 63) / 64;
    int nodeBlocks = (NN + 3) / 4;

    // input layer (reads f32 node_attrs directly)
    gemm_attn<128, true><<<gemmBlocks, 256, 0, stream>>>(node_attrs, W_in, a_src_in, a_dst_in, h, asrc, adst);
    edge_agg<0><<<nodeBlocks, 256, 0, stream>>>(rng, esrc, h, asrc, adst, b_in, ixbuf, x16,
                                                nullptr, nullptr, nullptr, nullptr, nullptr, nullptr);

    // 5 mid layers (shared weights), then the 6th mid agg fused with out-projection
    for (int l = 0; l < 5; ++l) {
        gemm_attn<64, false><<<gemmBlocks, 256, 0, stream>>>(x16, W_mid, a_src_mid, a_dst_mid, h, asrc, adst);
        edge_agg<1><<<nodeBlocks, 256, 0, stream>>>(rng, esrc, h, asrc, adst, b_mid, ixbuf, x16,
                                                    nullptr, nullptr, nullptr, nullptr, nullptr, nullptr);
    }
    gemm_attn<64, false><<<gemmBlocks, 256, 0, stream>>>(x16, W_mid, a_src_mid, a_dst_mid, h, asrc, adst);
    edge_agg<2><<<nodeBlocks, 256, 0, stream>>>(rng, esrc, h, asrc, adst, b_mid, ixbuf, nullptr,
                                                W_out, a_src_out, a_dst_out, h_o, asrc_o, adst_o);

    // final softmax-aggregation + sigmoid
    edge_agg_out<<<nodeBlocks, 256, 0, stream>>>(rng, esrc, h_o, asrc_o, adst_o, b_out, out);
}